// Round 12
// baseline (125.273 us; speedup 1.0000x reference)
//
#include <hip/hip_runtime.h>
#include <hip/hip_bf16.h>
#include <math.h>

// Sizes (fixed by the problem)
#define B 8
#define MEM_LEN 512
#define DEC_LEN 32
#define HDIM 1024
#define M1 513
#define PM_ROWS (B * M1)   // 4104
#define AROWS 4224         // 66*64 padded pm rows

// Finite -inf stand-in (exact -inf makes |ref-out| = NaN in the harness check).
#define NEG_BIG (-1e30f)
// 2*log2(e): tanh(x) = 1 - 2*rcp(1 + exp2(C2*x)). W scaled by C2 at staging;
// GEMM epilogue stores Em = exp2(C2*pm) (bf16), Ed = exp2(C2*pd) (f32):
// score inner loop = mul + add + rcp + fma (1 transcendental).
#define C2F 2.885390081777927f

#if __has_builtin(__builtin_amdgcn_exp2f)
#define EXP2(x) __builtin_amdgcn_exp2f(x)
#else
#define EXP2(x) exp2f(x)
#endif
#define RCP(x) __builtin_amdgcn_rcpf(x)
#define SCHED_FENCE() __builtin_amdgcn_sched_barrier(0)

typedef __bf16 bfv8 __attribute__((ext_vector_type(8)));
typedef float  f4   __attribute__((ext_vector_type(4)));
typedef float  f8   __attribute__((ext_vector_type(8)));

__device__ __forceinline__ bfv8 pack8s(float4 x, float4 y, float s) {
    bfv8 o;
    o[0] = (__bf16)(x.x * s); o[1] = (__bf16)(x.y * s);
    o[2] = (__bf16)(x.z * s); o[3] = (__bf16)(x.w * s);
    o[4] = (__bf16)(y.x * s); o[5] = (__bf16)(y.y * s);
    o[6] = (__bf16)(y.z * s); o[7] = (__bf16)(y.w * s);
    return o;
}

// ---------------------------------------------------------------------------
// Kernel 1: fused convert+GEMM. LDS-staged bf16 MFMA GEMM reading f32 sources
// directly (R11 structure + R6's staging-side conversion, now with the fixed
// pipeline: fully-unrolled kt loop => literal buffer indices; next-tile global
// loads issued BEFORE current tile's compute; T2 XOR chunk swizzle on both
// ds_write and ds_read (rule #21); coalesced 256B global segments).
//   blocks bx<66 : A = mem_full rows (term/mem/zero-pad) f32, W=C2*W_mem -> Em (bf16)
//   blocks bx>=66: A = dec_hid f32, W=C2*W_dec -> Ed (f32)
// Epilogue: out = exp2(acc + C2*bias).
// Tile 64x64, BK=64, 4 waves (2x2) of 32x32; LDS 32KB -> 4 blocks/CU.
// Chunked-bijective XCD swizzle (1120 = 8*140).
// Layouts (HW-verified m89/m91): A/B frag lane l -> row (l&15), k=(l>>4)*8+j;
// C/D: col = l&15, row = (l>>4)*4 + reg.
// ---------------------------------------------------------------------------
__global__ __launch_bounds__(256, 4) void gemm_f(
        const float* __restrict__ mem, const float* __restrict__ term,
        const float* __restrict__ dec_hid,
        const float* __restrict__ W_mem, const float* __restrict__ W_dec,
        const float* __restrict__ b_mem, const float* __restrict__ b_dec,
        __bf16* __restrict__ pmb, float* __restrict__ pdf) {
    __shared__ __align__(16) __bf16 Als[2][64 * 64];   // 2 x 8KB
    __shared__ __align__(16) __bf16 Bls[2][64 * 64];   // 2 x 8KB

    int orig = blockIdx.x;                       // 0..1119
    int wg   = (orig & 7) * 140 + (orig >> 3);   // chunked XCD swizzle (8*140)
    int bx   = wg >> 4;                          // 0..69
    int by   = wg & 15;

    bool isMem = bx < 66;
    const float* Wsel = isMem ? W_mem : W_dec;
    const float* bsel = isMem ? b_mem : b_dec;
    int row0 = isMem ? bx * 64 : (bx - 66) * 64;
    int n0b  = by * 64;

    int t = threadIdx.x;
    int r0 = t >> 3, g0 = t & 7;                 // rows 0..31, chunk 0..7
    int r1 = r0 + 32;                            // rows 32..63, same chunk
    int ds0 = r0 * 128 + ((g0 ^ (r0 & 7)) << 4); // swizzled LDS byte offsets
    int ds1 = r1 * 128 + ((g0 ^ (r1 & 7)) << 4);

    // A-source row pointers (nullptr => zero pad row)
    const float* aS0;
    const float* aS1;
    if (isMem) {
        int grow = row0 + r0;
        if (grow < PM_ROWS) {
            int bb = grow / M1, mm = grow - bb * M1;
            aS0 = (mm == 0) ? term : mem + ((size_t)(bb * MEM_LEN + mm - 1)) * 512;
        } else aS0 = nullptr;
        grow = row0 + r1;
        if (grow < PM_ROWS) {
            int bb = grow / M1, mm = grow - bb * M1;
            aS1 = (mm == 0) ? term : mem + ((size_t)(bb * MEM_LEN + mm - 1)) * 512;
        } else aS1 = nullptr;
    } else {
        aS0 = dec_hid + (size_t)(row0 + r0) * 512;
        aS1 = dec_hid + (size_t)(row0 + r1) * 512;
    }
    const float* wS0 = Wsel + (size_t)(n0b + r0) * 512;
    const float* wS1 = Wsel + (size_t)(n0b + r1) * 512;
    const float4 Z4 = make_float4(0.f, 0.f, 0.f, 0.f);
    int co = g0 * 8;                             // chunk element offset

    int w = t >> 6, l = t & 63;
    int m0w = (w >> 1) * 32, n0w = (w & 1) * 32;
    int lr = l & 15, lq = l >> 4;

    f4 acc[2][2] = {};

    // prologue: stage K-tile 0 into buf 0
    {
        float4 ax0 = aS0 ? *(const float4*)(aS0 + co)     : Z4;
        float4 ax1 = aS0 ? *(const float4*)(aS0 + co + 4) : Z4;
        float4 ay0 = aS1 ? *(const float4*)(aS1 + co)     : Z4;
        float4 ay1 = aS1 ? *(const float4*)(aS1 + co + 4) : Z4;
        float4 bx0 = *(const float4*)(wS0 + co);
        float4 bx1 = *(const float4*)(wS0 + co + 4);
        float4 by0 = *(const float4*)(wS1 + co);
        float4 by1 = *(const float4*)(wS1 + co + 4);
        *(bfv8*)((char*)&Als[0][0] + ds0) = pack8s(ax0, ax1, 1.f);
        *(bfv8*)((char*)&Als[0][0] + ds1) = pack8s(ay0, ay1, 1.f);
        *(bfv8*)((char*)&Bls[0][0] + ds0) = pack8s(bx0, bx1, C2F);
        *(bfv8*)((char*)&Bls[0][0] + ds1) = pack8s(by0, by1, C2F);
    }
    __syncthreads();

    #pragma unroll
    for (int kt = 0; kt < 8; ++kt) {
        const int cur = kt & 1;
        float4 ax0, ax1, ay0, ay1, bx0, bx1, by0, by1;
        if (kt < 7) {                      // issue next-tile loads EARLY
            const int kn = (kt + 1) * 64 + co;
            ax0 = aS0 ? *(const float4*)(aS0 + kn)     : Z4;
            ax1 = aS0 ? *(const float4*)(aS0 + kn + 4) : Z4;
            ay0 = aS1 ? *(const float4*)(aS1 + kn)     : Z4;
            ay1 = aS1 ? *(const float4*)(aS1 + kn + 4) : Z4;
            bx0 = *(const float4*)(wS0 + kn);
            bx1 = *(const float4*)(wS0 + kn + 4);
            by0 = *(const float4*)(wS1 + kn);
            by1 = *(const float4*)(wS1 + kn + 4);
        }
        SCHED_FENCE();                     // keep load issue above compute
        bfv8 aF[2][2], bF[2][2];
        #pragma unroll
        for (int kk = 0; kk < 2; ++kk) {
            int g = kk * 4 + lq;
            #pragma unroll
            for (int i = 0; i < 2; ++i) {
                int rA = m0w + i * 16 + lr;
                aF[kk][i] = *(const bfv8*)((char*)&Als[cur][0] + rA * 128 + ((g ^ (rA & 7)) << 4));
                int rB = n0w + i * 16 + lr;
                bF[kk][i] = *(const bfv8*)((char*)&Bls[cur][0] + rB * 128 + ((g ^ (rB & 7)) << 4));
            }
        }
        #pragma unroll
        for (int kk = 0; kk < 2; ++kk) {
            acc[0][0] = __builtin_amdgcn_mfma_f32_16x16x32_bf16(aF[kk][0], bF[kk][0], acc[0][0], 0, 0, 0);
            acc[0][1] = __builtin_amdgcn_mfma_f32_16x16x32_bf16(aF[kk][0], bF[kk][1], acc[0][1], 0, 0, 0);
            acc[1][0] = __builtin_amdgcn_mfma_f32_16x16x32_bf16(aF[kk][1], bF[kk][0], acc[1][0], 0, 0, 0);
            acc[1][1] = __builtin_amdgcn_mfma_f32_16x16x32_bf16(aF[kk][1], bF[kk][1], acc[1][1], 0, 0, 0);
        }
        if (kt < 7) {                      // convert + write next tile
            const int nxt = cur ^ 1;
            *(bfv8*)((char*)&Als[nxt][0] + ds0) = pack8s(ax0, ax1, 1.f);
            *(bfv8*)((char*)&Als[nxt][0] + ds1) = pack8s(ay0, ay1, 1.f);
            *(bfv8*)((char*)&Bls[nxt][0] + ds0) = pack8s(bx0, bx1, C2F);
            *(bfv8*)((char*)&Bls[nxt][0] + ds1) = pack8s(by0, by1, C2F);
        }
        __syncthreads();
    }

    // epilogue: Em (bf16) / Ed (f32) = exp2(acc + C2*bias)
    int crow = lq * 4;
    int ccol = lr;
    #pragma unroll
    for (int j = 0; j < 2; ++j) {
        int col = n0b + n0w + j * 16 + ccol;
        float bv = bsel[col] * C2F;
        #pragma unroll
        for (int i = 0; i < 2; ++i) {
            #pragma unroll
            for (int r = 0; r < 4; ++r) {
                int row = row0 + m0w + i * 16 + crow + r;
                float e = EXP2(acc[i][j][r] + bv);
                if (isMem) pmb[(size_t)row * HDIM + col] = (__bf16)e;
                else       pdf[(size_t)row * HDIM + col] = e;
            }
        }
    }
}

// ---------------------------------------------------------------------------
// Kernel 2: score[b,d,m] = SumW - sum_h 2*w[h]*rcp(1 + Em*Ed)
// Em bf16 (cvt once per row, amortized over 4 d); Ed f32 in LDS (16KB, no
// per-instance cvt). Inner loop per element-instance: mul+add+rcp+fma =
// 3 VALU + 1 trans. Grid: b(8) x dgroup(8, 4 d) x mchunk(17); b=bid&7 -> XCD.
// ---------------------------------------------------------------------------
__global__ __launch_bounds__(256, 4) void score7(
        const __bf16* __restrict__ pm, const float* __restrict__ pdf,
        const float* __restrict__ w_score,
        const unsigned char* __restrict__ mem_mask,
        const unsigned char* __restrict__ dec_mask,
        const unsigned char* __restrict__ dup_mask,
        float* __restrict__ sc) {
    __shared__ float pdl[4][HDIM];         // 16 KB (Ed, f32)
    int bid = blockIdx.x;
    int b    = bid & 7;
    int rest = bid >> 3;
    int dg   = rest & 7;
    int mc   = rest >> 3;                  // 0..16
    int t = threadIdx.x, w = t >> 6, l = t & 63;
    int bd0 = b * DEC_LEN + dg * 4;

    {   // cooperative stage: thread t copies 16 f32 of Ed row d = t>>6
        int d  = t >> 6;
        int h0 = (t & 63) * 16;
        const f4* src = (const f4*)(pdf + (size_t)(bd0 + d) * HDIM + h0);
        f4* dst = (f4*)&pdl[d][h0];
        dst[0] = src[0]; dst[1] = src[1]; dst[2] = src[2]; dst[3] = src[3];
    }

    f8 w22[2];
    float sumw_l = 0.f;
    #pragma unroll
    for (int half = 0; half < 2; ++half) {
        f8 wv = *(const f8*)(w_score + half * 512 + l * 8);
        #pragma unroll
        for (int j = 0; j < 8; ++j) {
            sumw_l += wv[j];
            w22[half][j] = wv[j] * 2.f;
        }
    }
    #pragma unroll
    for (int off = 32; off; off >>= 1) sumw_l += __shfl_xor(sumw_l, off, 64);
    float sumw_all = sumw_l;

    bool dm[4];
    #pragma unroll
    for (int d = 0; d < 4; ++d) dm[d] = dec_mask[bd0 + d] != 0;
    const unsigned char* dup0 = dup_mask + (size_t)bd0 * M1;

    __syncthreads();

    int mbase = mc * 32 + w * 8;
    for (int i = 0; i < 8; ++i) {
        int m = mbase + i;
        if (m >= M1) break;                // wave-uniform
        bool memm = (m > 0) && (mem_mask[b * MEM_LEN + m - 1] != 0);
        if (memm) {                        // wave-uniform skip (~10% rows)
            if (l == 0) {
                #pragma unroll
                for (int d = 0; d < 4; ++d)
                    sc[(size_t)(bd0 + d) * M1 + m] = NEG_BIG;
            }
            continue;
        }
        const __bf16* pmr = pm + ((size_t)(b * M1 + m)) * HDIM + l * 8;
        bfv8 p0 = *(const bfv8*)(pmr);
        bfv8 p1 = *(const bfv8*)(pmr + 512);
        f8 pf0, pf1;                       // cvt once per row (amortized 4x)
        #pragma unroll
        for (int j = 0; j < 8; ++j) { pf0[j] = (float)p0[j]; pf1[j] = (float)p1[j]; }
        float ac[4][2] = {};
        #pragma unroll
        for (int d = 0; d < 4; ++d) {
            f4 q0a = *(const f4*)&pdl[d][l * 8];
            f4 q0b = *(const f4*)&pdl[d][l * 8 + 4];
            f4 q1a = *(const f4*)&pdl[d][512 + l * 8];
            f4 q1b = *(const f4*)&pdl[d][512 + l * 8 + 4];
            #pragma unroll
            for (int j = 0; j < 4; ++j) {
                float e0 = pf0[j] * q0a[j];
                ac[d][0] = fmaf(w22[0][j], RCP(e0 + 1.f), ac[d][0]);
                float e1 = pf0[j + 4] * q0b[j];
                ac[d][0] = fmaf(w22[0][j + 4], RCP(e1 + 1.f), ac[d][0]);
                float e2 = pf1[j] * q1a[j];
                ac[d][1] = fmaf(w22[1][j], RCP(e2 + 1.f), ac[d][1]);
                float e3 = pf1[j + 4] * q1b[j];
                ac[d][1] = fmaf(w22[1][j + 4], RCP(e3 + 1.f), ac[d][1]);
            }
        }
        float a0 = ac[0][0] + ac[0][1];
        float a1 = ac[1][0] + ac[1][1];
        float a2 = ac[2][0] + ac[2][1];
        float a3 = ac[3][0] + ac[3][1];
        #pragma unroll
        for (int off = 32; off; off >>= 1) {
            a0 += __shfl_xor(a0, off, 64);
            a1 += __shfl_xor(a1, off, 64);
            a2 += __shfl_xor(a2, off, 64);
            a3 += __shfl_xor(a3, off, 64);
        }
        float s[4];
        s[0] = sumw_all - a0;
        s[1] = sumw_all - a1;
        s[2] = sumw_all - a2;
        s[3] = sumw_all - a3;
        #pragma unroll
        for (int d = 0; d < 4; ++d) {
            bool kill = (!dm[d] && dup0[(size_t)d * M1 + m]);
            s[d] = kill ? NEG_BIG : s[d];
        }
        if (l == 0) {
            #pragma unroll
            for (int d = 0; d < 4; ++d)
                sc[(size_t)(bd0 + d) * M1 + m] = s[d];
        }
    }
}

// ---------------------------------------------------------------------------
// Kernel 3: row-wise log_softmax over 513 entries. One block per (b,d).
// ---------------------------------------------------------------------------
__global__ __launch_bounds__(512) void softmax_k(const float* __restrict__ sc,
                                                 float* __restrict__ out) {
    __shared__ float red[512];
    int bd = blockIdx.x, t = threadIdx.x;
    const float* row = sc + (size_t)bd * M1;
    float v = row[t];
    float v512 = row[512];
    float lm = (t == 0) ? fmaxf(v, v512) : v;
    red[t] = lm;
    __syncthreads();
    for (int s = 256; s > 0; s >>= 1) {
        if (t < s) red[t] = fmaxf(red[t], red[t + s]);
        __syncthreads();
    }
    float mx = red[0];
    __syncthreads();
    float le = __expf(v - mx);             // exp(NEG_BIG - mx) == 0 exactly
    if (t == 0) le += __expf(v512 - mx);
    red[t] = le;
    __syncthreads();
    for (int s = 256; s > 0; s >>= 1) {
        if (t < s) red[t] += red[t + s];
        __syncthreads();
    }
    float lse = mx + __logf(red[0]);
    float* orow = out + (size_t)bd * M1;
    orow[t] = v - lse;
    if (t == 0) orow[512] = v512 - lse;
}

// ---------------------------------------------------------------------------
extern "C" void kernel_launch(void* const* d_in, const int* in_sizes, int n_in,
                              void* d_out, int out_size, void* d_ws, size_t ws_size,
                              hipStream_t stream) {
    const float* mem      = (const float*)d_in[0];
    const float* dec_hid  = (const float*)d_in[1];
    const unsigned char* mem_mask = (const unsigned char*)d_in[2];
    const unsigned char* dec_mask = (const unsigned char*)d_in[3];
    const unsigned char* dup_mask = (const unsigned char*)d_in[4];
    const float* term     = (const float*)d_in[5];
    const float* W_mem    = (const float*)d_in[6];
    const float* b_mem    = (const float*)d_in[7];
    const float* W_dec    = (const float*)d_in[8];
    const float* b_dec    = (const float*)d_in[9];
    const float* w_score  = (const float*)d_in[10];
    // d_in[11] = b_score : unused (log_softmax is shift-invariant)

    float* out = (float*)d_out;
    char* ws = (char*)d_ws;
    __bf16* pmb = (__bf16*)ws;                               // 4224*1024*2 = 8,650,752
    float*  pdf = (float*)(pmb + (size_t)AROWS * HDIM);      //  256*1024*4 = 1,048,576
    float*  sc  = pdf + (size_t)256 * HDIM;                  //  256*513*4  =   525,312

    gemm_f<<<1120, 256, 0, stream>>>(mem, term, dec_hid, W_mem, W_dec,
                                     b_mem, b_dec, pmb, pdf);
    score7<<<8 * 8 * 17, 256, 0, stream>>>(pmb, pdf, w_score,
                                           mem_mask, dec_mask, dup_mask, sc);
    softmax_k<<<B * DEC_LEN, 512, 0, stream>>>(sc, out);
}

// Round 13
// 52.027 us; speedup vs baseline: 2.4078x; 2.4078x over previous
//
#include <hip/hip_runtime.h>
#include <hip/hip_bf16.h>
#include <math.h>

// Sizes (fixed by the problem)
#define B 8
#define MEM_LEN 512
#define DEC_LEN 32
#define HDIM 1024
#define M1 513
#define PM_ROWS (B * M1)   // 4104
#define AROWS 4224         // 66*64 padded pm rows

// Finite -inf stand-in (exact -inf makes |ref-out| = NaN in the harness check).
#define NEG_BIG (-1e30f)
// 2*log2(e): tanh(x) = 1 - 2*rcp(1 + exp2(C2*x)). W pre-scaled by C2 in
// convert_all; GEMM epilogue stores Em = exp2(C2*pm) (bf16) and
// Ed = exp2(C2*pd) (f32): score inner loop = mul + add + rcp + fma.
#define C2F 2.885390081777927f

#if __has_builtin(__builtin_amdgcn_exp2f)
#define EXP2(x) __builtin_amdgcn_exp2f(x)
#else
#define EXP2(x) exp2f(x)
#endif
#define RCP(x) __builtin_amdgcn_rcpf(x)
#define SCHED_FENCE() __builtin_amdgcn_sched_barrier(0)

typedef __bf16 bfv8 __attribute__((ext_vector_type(8)));
typedef float  f4   __attribute__((ext_vector_type(4)));
typedef float  f8   __attribute__((ext_vector_type(8)));

// ---------------------------------------------------------------------------
// Kernel 1: convert GEMM operands to bf16 (assemble mem_full + zero pad;
// weights pre-scaled by C2). One thread = 8 elements. R12 lesson: conversion
// lives HERE (latency-insensitive streaming kernel), never in the GEMM
// staging path (conditional f32 loads + cvt chains there serialized the
// pipeline 10x: R6=104us, R12=100us vs R11=fast).
// ---------------------------------------------------------------------------
#define N_MF  (AROWS * 512 / 8)         // 270336
#define N_DEC (256 * 512 / 8)           // 16384
#define N_W   (1024 * 512 / 8)          // 65536
#define N_CVT (N_MF + N_DEC + 2 * N_W)  // 417792 = 1632*256

__global__ __launch_bounds__(256) void convert_all(
        const float* __restrict__ mem, const float* __restrict__ term,
        const float* __restrict__ dec_hid,
        const float* __restrict__ W_mem, const float* __restrict__ W_dec,
        __bf16* __restrict__ mfb, __bf16* __restrict__ decb,
        __bf16* __restrict__ wmb, __bf16* __restrict__ wdb) {
    int idx = blockIdx.x * 256 + threadIdx.x;
    float4 v0 = make_float4(0.f, 0.f, 0.f, 0.f), v1 = v0;
    float scale = 1.f;
    __bf16* dst;
    if (idx < N_MF) {
        int row = idx >> 6;          // 64 chunks of 8 per 512-wide row
        int c8  = idx & 63;
        dst = mfb + (size_t)idx * 8;
        if (row < PM_ROWS) {
            int b = row / M1, m = row - b * M1;
            const float* src = (m == 0) ? (term + c8 * 8)
                                        : (mem + ((size_t)(b * MEM_LEN + m - 1)) * 512 + c8 * 8);
            v0 = ((const float4*)src)[0];
            v1 = ((const float4*)src)[1];
        } // else rows >= 4104 stay zero (GEMM pad)
    } else if (idx < N_MF + N_DEC) {
        int j = idx - N_MF;
        dst = decb + (size_t)j * 8;
        v0 = ((const float4*)dec_hid)[j * 2];
        v1 = ((const float4*)dec_hid)[j * 2 + 1];
    } else if (idx < N_MF + N_DEC + N_W) {
        int j = idx - N_MF - N_DEC;
        dst = wmb + (size_t)j * 8;
        v0 = ((const float4*)W_mem)[j * 2];
        v1 = ((const float4*)W_mem)[j * 2 + 1];
        scale = C2F;
    } else {
        int j = idx - N_MF - N_DEC - N_W;
        dst = wdb + (size_t)j * 8;
        v0 = ((const float4*)W_dec)[j * 2];
        v1 = ((const float4*)W_dec)[j * 2 + 1];
        scale = C2F;
    }
    bfv8 o;
    o[0] = (__bf16)(v0.x * scale); o[1] = (__bf16)(v0.y * scale);
    o[2] = (__bf16)(v0.z * scale); o[3] = (__bf16)(v0.w * scale);
    o[4] = (__bf16)(v1.x * scale); o[5] = (__bf16)(v1.y * scale);
    o[6] = (__bf16)(v1.z * scale); o[7] = (__bf16)(v1.w * scale);
    *(bfv8*)dst = o;
}

// ---------------------------------------------------------------------------
// Kernel 2: LDS-staged bf16 MFMA GEMM — R11's proven-fast structure, verbatim
// except the epilogue (Em bf16 / Ed f32). Key properties (all measured):
//  * staging loads UNCONDITIONAL bf16 16B, 8 lanes = 128B contiguous
//  * fully-unrolled kt loop => literal LDS buffer indices
//  * next-tile loads issued BEFORE current compute (counted vmcnt)
//  * T2 XOR chunk swizzle on both ds_write and ds_read (rule #21)
//  * chunked-bijective XCD swizzle (1120 = 8*140)
// Tile 64x64, BK=64, 4 waves (2x2) of 32x32; LDS 32KB.
// Layouts (HW-verified m89/m91): A/B frag lane l -> row (l&15), k=(l>>4)*8+j;
// C/D: col = l&15, row = (l>>4)*4 + reg.
// ---------------------------------------------------------------------------
__global__ __launch_bounds__(256, 4) void gemm_ls(
        const __bf16* __restrict__ mfb, const __bf16* __restrict__ decb,
        const __bf16* __restrict__ wmb, const __bf16* __restrict__ wdb,
        const float* __restrict__ b_mem, const float* __restrict__ b_dec,
        __bf16* __restrict__ pmb, float* __restrict__ pdf) {
    __shared__ __align__(16) __bf16 Als[2][64 * 64];   // 2 x 8KB
    __shared__ __align__(16) __bf16 Bls[2][64 * 64];   // 2 x 8KB

    int orig = blockIdx.x;                       // 0..1119
    int wg   = (orig & 7) * 140 + (orig >> 3);   // chunked XCD swizzle (8*140)
    int bx   = wg >> 4;                          // 0..69
    int by   = wg & 15;

    bool isMem = bx < 66;
    const __bf16* A  = isMem ? mfb : decb;
    const __bf16* Wb = isMem ? wmb : wdb;
    const float* bsel = isMem ? b_mem : b_dec;
    int row0 = isMem ? bx * 64 : (bx - 66) * 64;
    int n0b  = by * 64;

    int t = threadIdx.x;
    int r0 = t >> 3,          g0 = t & 7;
    int r1 = (t + 256) >> 3,  g1 = t & 7;
    int ds0 = r0 * 128 + ((g0 ^ (r0 & 7)) << 4);   // swizzled byte offsets
    int ds1 = r1 * 128 + ((g1 ^ (r1 & 7)) << 4);
    const __bf16* aSrc0 = A  + (size_t)(row0 + r0) * 512 + g0 * 8;
    const __bf16* aSrc1 = A  + (size_t)(row0 + r1) * 512 + g1 * 8;
    const __bf16* bSrc0 = Wb + (size_t)(n0b + r0) * 512 + g0 * 8;
    const __bf16* bSrc1 = Wb + (size_t)(n0b + r1) * 512 + g1 * 8;

    int w = t >> 6, l = t & 63;
    int m0w = (w >> 1) * 32, n0w = (w & 1) * 32;
    int lr = l & 15, lq = l >> 4;

    f4 acc[2][2] = {};

    // prologue: stage K-tile 0 into buf 0
    {
        bfv8 a0 = *(const bfv8*)(aSrc0);
        bfv8 a1 = *(const bfv8*)(aSrc1);
        bfv8 b0 = *(const bfv8*)(bSrc0);
        bfv8 b1 = *(const bfv8*)(bSrc1);
        *(bfv8*)((char*)&Als[0][0] + ds0) = a0;
        *(bfv8*)((char*)&Als[0][0] + ds1) = a1;
        *(bfv8*)((char*)&Bls[0][0] + ds0) = b0;
        *(bfv8*)((char*)&Bls[0][0] + ds1) = b1;
    }
    __syncthreads();

    #pragma unroll
    for (int kt = 0; kt < 8; ++kt) {
        const int cur = kt & 1;
        bfv8 na0, na1, nb0, nb1;
        if (kt < 7) {                      // issue next-tile loads EARLY
            const int kn = (kt + 1) * 64;
            na0 = *(const bfv8*)(aSrc0 + kn);
            na1 = *(const bfv8*)(aSrc1 + kn);
            nb0 = *(const bfv8*)(bSrc0 + kn);
            nb1 = *(const bfv8*)(bSrc1 + kn);
        }
        SCHED_FENCE();                     // keep load issue above compute
        // fragments: 8 ds_read_b128 (swizzled, conflict-free) then 8 MFMA
        bfv8 aF[2][2], bF[2][2];
        #pragma unroll
        for (int kk = 0; kk < 2; ++kk) {
            int g = kk * 4 + lq;
            #pragma unroll
            for (int i = 0; i < 2; ++i) {
                int rA = m0w + i * 16 + lr;
                aF[kk][i] = *(const bfv8*)((char*)&Als[cur][0] + rA * 128 + ((g ^ (rA & 7)) << 4));
                int rB = n0w + i * 16 + lr;
                bF[kk][i] = *(const bfv8*)((char*)&Bls[cur][0] + rB * 128 + ((g ^ (rB & 7)) << 4));
            }
        }
        #pragma unroll
        for (int kk = 0; kk < 2; ++kk) {
            acc[0][0] = __builtin_amdgcn_mfma_f32_16x16x32_bf16(aF[kk][0], bF[kk][0], acc[0][0], 0, 0, 0);
            acc[0][1] = __builtin_amdgcn_mfma_f32_16x16x32_bf16(aF[kk][0], bF[kk][1], acc[0][1], 0, 0, 0);
            acc[1][0] = __builtin_amdgcn_mfma_f32_16x16x32_bf16(aF[kk][1], bF[kk][0], acc[1][0], 0, 0, 0);
            acc[1][1] = __builtin_amdgcn_mfma_f32_16x16x32_bf16(aF[kk][1], bF[kk][1], acc[1][1], 0, 0, 0);
        }
        if (kt < 7) {                      // write next tile to other buffer
            const int nxt = cur ^ 1;
            *(bfv8*)((char*)&Als[nxt][0] + ds0) = na0;
            *(bfv8*)((char*)&Als[nxt][0] + ds1) = na1;
            *(bfv8*)((char*)&Bls[nxt][0] + ds0) = nb0;
            *(bfv8*)((char*)&Bls[nxt][0] + ds1) = nb1;
        }
        __syncthreads();
    }

    // epilogue: Em = exp2(acc + C2*bias) -> bf16 (pm); Ed -> f32 (pd)
    int crow = lq * 4;
    int ccol = lr;
    #pragma unroll
    for (int j = 0; j < 2; ++j) {
        int col = n0b + n0w + j * 16 + ccol;
        float bv = bsel[col] * C2F;
        #pragma unroll
        for (int i = 0; i < 2; ++i) {
            #pragma unroll
            for (int r = 0; r < 4; ++r) {
                int row = row0 + m0w + i * 16 + crow + r;
                float e = EXP2(acc[i][j][r] + bv);
                if (isMem) pmb[(size_t)row * HDIM + col] = (__bf16)e;
                else       pdf[(size_t)row * HDIM + col] = e;
            }
        }
    }
}

// ---------------------------------------------------------------------------
// Kernel 3: score[b,d,m] = SumW - sum_h 2*w[h]*rcp(1 + Em*Ed)
// Em bf16 (cvt once per row, amortized over 4 d); Ed f32 in LDS (16KB, no
// per-instance cvt). Inner loop per element-instance: mul+add+rcp+fma.
// Grid: b(8) x dgroup(8, 4 d) x mchunk(17); b=bid&7 -> XCD.
// ---------------------------------------------------------------------------
__global__ __launch_bounds__(256, 4) void score7(
        const __bf16* __restrict__ pm, const float* __restrict__ pdf,
        const float* __restrict__ w_score,
        const unsigned char* __restrict__ mem_mask,
        const unsigned char* __restrict__ dec_mask,
        const unsigned char* __restrict__ dup_mask,
        float* __restrict__ sc) {
    __shared__ float pdl[4][HDIM];         // 16 KB (Ed, f32)
    int bid = blockIdx.x;
    int b    = bid & 7;
    int rest = bid >> 3;
    int dg   = rest & 7;
    int mc   = rest >> 3;                  // 0..16
    int t = threadIdx.x, w = t >> 6, l = t & 63;
    int bd0 = b * DEC_LEN + dg * 4;

    {   // cooperative stage: thread t copies 16 f32 of Ed row d = t>>6
        int d  = t >> 6;
        int h0 = (t & 63) * 16;
        const f4* src = (const f4*)(pdf + (size_t)(bd0 + d) * HDIM + h0);
        f4* dst = (f4*)&pdl[d][h0];
        dst[0] = src[0]; dst[1] = src[1]; dst[2] = src[2]; dst[3] = src[3];
    }

    f8 w22[2];
    float sumw_l = 0.f;
    #pragma unroll
    for (int half = 0; half < 2; ++half) {
        f8 wv = *(const f8*)(w_score + half * 512 + l * 8);
        #pragma unroll
        for (int j = 0; j < 8; ++j) {
            sumw_l += wv[j];
            w22[half][j] = wv[j] * 2.f;
        }
    }
    #pragma unroll
    for (int off = 32; off; off >>= 1) sumw_l += __shfl_xor(sumw_l, off, 64);
    float sumw_all = sumw_l;

    bool dm[4];
    #pragma unroll
    for (int d = 0; d < 4; ++d) dm[d] = dec_mask[bd0 + d] != 0;
    const unsigned char* dup0 = dup_mask + (size_t)bd0 * M1;

    __syncthreads();

    int mbase = mc * 32 + w * 8;
    for (int i = 0; i < 8; ++i) {
        int m = mbase + i;
        if (m >= M1) break;                // wave-uniform
        bool memm = (m > 0) && (mem_mask[b * MEM_LEN + m - 1] != 0);
        if (memm) {                        // wave-uniform skip (~10% rows)
            if (l == 0) {
                #pragma unroll
                for (int d = 0; d < 4; ++d)
                    sc[(size_t)(bd0 + d) * M1 + m] = NEG_BIG;
            }
            continue;
        }
        const __bf16* pmr = pm + ((size_t)(b * M1 + m)) * HDIM + l * 8;
        bfv8 p0 = *(const bfv8*)(pmr);
        bfv8 p1 = *(const bfv8*)(pmr + 512);
        f8 pf0, pf1;                       // cvt once per row (amortized 4x)
        #pragma unroll
        for (int j = 0; j < 8; ++j) { pf0[j] = (float)p0[j]; pf1[j] = (float)p1[j]; }
        float ac[4][2] = {};
        #pragma unroll
        for (int d = 0; d < 4; ++d) {
            f4 q0a = *(const f4*)&pdl[d][l * 8];
            f4 q0b = *(const f4*)&pdl[d][l * 8 + 4];
            f4 q1a = *(const f4*)&pdl[d][512 + l * 8];
            f4 q1b = *(const f4*)&pdl[d][512 + l * 8 + 4];
            #pragma unroll
            for (int j = 0; j < 4; ++j) {
                float e0 = pf0[j] * q0a[j];
                ac[d][0] = fmaf(w22[0][j], RCP(e0 + 1.f), ac[d][0]);
                float e1 = pf0[j + 4] * q0b[j];
                ac[d][0] = fmaf(w22[0][j + 4], RCP(e1 + 1.f), ac[d][0]);
                float e2 = pf1[j] * q1a[j];
                ac[d][1] = fmaf(w22[1][j], RCP(e2 + 1.f), ac[d][1]);
                float e3 = pf1[j + 4] * q1b[j];
                ac[d][1] = fmaf(w22[1][j + 4], RCP(e3 + 1.f), ac[d][1]);
            }
        }
        float a0 = ac[0][0] + ac[0][1];
        float a1 = ac[1][0] + ac[1][1];
        float a2 = ac[2][0] + ac[2][1];
        float a3 = ac[3][0] + ac[3][1];
        #pragma unroll
        for (int off = 32; off; off >>= 1) {
            a0 += __shfl_xor(a0, off, 64);
            a1 += __shfl_xor(a1, off, 64);
            a2 += __shfl_xor(a2, off, 64);
            a3 += __shfl_xor(a3, off, 64);
        }
        float s[4];
        s[0] = sumw_all - a0;
        s[1] = sumw_all - a1;
        s[2] = sumw_all - a2;
        s[3] = sumw_all - a3;
        #pragma unroll
        for (int d = 0; d < 4; ++d) {
            bool kill = (!dm[d] && dup0[(size_t)d * M1 + m]);
            s[d] = kill ? NEG_BIG : s[d];
        }
        if (l == 0) {
            #pragma unroll
            for (int d = 0; d < 4; ++d)
                sc[(size_t)(bd0 + d) * M1 + m] = s[d];
        }
    }
}

// ---------------------------------------------------------------------------
// Kernel 4: row-wise log_softmax over 513 entries. One block per (b,d).
// ---------------------------------------------------------------------------
__global__ __launch_bounds__(512) void softmax_k(const float* __restrict__ sc,
                                                 float* __restrict__ out) {
    __shared__ float red[512];
    int bd = blockIdx.x, t = threadIdx.x;
    const float* row = sc + (size_t)bd * M1;
    float v = row[t];
    float v512 = row[512];
    float lm = (t == 0) ? fmaxf(v, v512) : v;
    red[t] = lm;
    __syncthreads();
    for (int s = 256; s > 0; s >>= 1) {
        if (t < s) red[t] = fmaxf(red[t], red[t + s]);
        __syncthreads();
    }
    float mx = red[0];
    __syncthreads();
    float le = __expf(v - mx);             // exp(NEG_BIG - mx) == 0 exactly
    if (t == 0) le += __expf(v512 - mx);
    red[t] = le;
    __syncthreads();
    for (int s = 256; s > 0; s >>= 1) {
        if (t < s) red[t] += red[t + s];
        __syncthreads();
    }
    float lse = mx + __logf(red[0]);
    float* orow = out + (size_t)bd * M1;
    orow[t] = v - lse;
    if (t == 0) orow[512] = v512 - lse;
}

// ---------------------------------------------------------------------------
extern "C" void kernel_launch(void* const* d_in, const int* in_sizes, int n_in,
                              void* d_out, int out_size, void* d_ws, size_t ws_size,
                              hipStream_t stream) {
    const float* mem      = (const float*)d_in[0];
    const float* dec_hid  = (const float*)d_in[1];
    const unsigned char* mem_mask = (const unsigned char*)d_in[2];
    const unsigned char* dec_mask = (const unsigned char*)d_in[3];
    const unsigned char* dup_mask = (const unsigned char*)d_in[4];
    const float* term     = (const float*)d_in[5];
    const float* W_mem    = (const float*)d_in[6];
    const float* b_mem    = (const float*)d_in[7];
    const float* W_dec    = (const float*)d_in[8];
    const float* b_dec    = (const float*)d_in[9];
    const float* w_score  = (const float*)d_in[10];
    // d_in[11] = b_score : unused (log_softmax is shift-invariant)

    float* out = (float*)d_out;
    char* ws = (char*)d_ws;
    __bf16* mfb  = (__bf16*)ws;                              // 4224*512*2  = 4,325,376
    __bf16* decb = mfb + (size_t)AROWS * 512;                //  256*512*2  =   262,144
    __bf16* wmb  = decb + (size_t)256 * 512;                 // 1024*512*2  = 1,048,576
    __bf16* wdb  = wmb + (size_t)1024 * 512;                 // 1024*512*2  = 1,048,576
    __bf16* pmb  = wdb + (size_t)1024 * 512;                 // 4224*1024*2 = 8,650,752
    float*  pdf  = (float*)(pmb + (size_t)AROWS * HDIM);     //  256*1024*4 = 1,048,576
    float*  sc   = pdf + (size_t)256 * HDIM;                 //  256*513*4  =   525,312

    convert_all<<<N_CVT / 256, 256, 0, stream>>>(mem, term, dec_hid, W_mem, W_dec,
                                                 mfb, decb, wmb, wdb);
    gemm_ls<<<1120, 256, 0, stream>>>(mfb, decb, wmb, wdb, b_mem, b_dec, pmb, pdf);
    score7<<<8 * 8 * 17, 256, 0, stream>>>(pmb, pdf, w_score,
                                           mem_mask, dec_mask, dup_mask, sc);
    softmax_k<<<B * DEC_LEN, 512, 0, stream>>>(sc, out);
}

// Round 14
// 50.108 us; speedup vs baseline: 2.5001x; 1.0383x over previous
//
#include <hip/hip_runtime.h>
#include <hip/hip_bf16.h>
#include <math.h>

// Sizes (fixed by the problem)
#define B 8
#define MEM_LEN 512
#define DEC_LEN 32
#define HDIM 1024
#define M1 513
#define PM_ROWS (B * M1)   // 4104
#define AROWS 4224         // 66*64 padded pm rows

// Finite -inf stand-in (exact -inf makes |ref-out| = NaN in the harness check).
#define NEG_BIG (-1e30f)
// 2*log2(e): tanh(x) = 1 - 2*rcp(1 + exp2(C2*x)). W pre-scaled by C2 in
// convert_all; GEMM epilogue stores Em = exp2(C2*pm) (bf16) and
// Ed = exp2(C2*pd) (f32). Score uses a 4-way rational combine:
//   sum_i wi/ti = [ (w1 t2 + w2 t1) t3 t4 + (w3 t4 + w4 t3) t1 t2 ] / (t1..t4)
// -> ONE v_rcp per 4 elements (trans instr = 16 cyc issue on CDNA4; R10->R11
// delta measured 13us for removing 1 trans/elem).
#define C2F 2.885390081777927f

#if __has_builtin(__builtin_amdgcn_exp2f)
#define EXP2(x) __builtin_amdgcn_exp2f(x)
#else
#define EXP2(x) exp2f(x)
#endif
#define RCP(x) __builtin_amdgcn_rcpf(x)
#define SCHED_FENCE() __builtin_amdgcn_sched_barrier(0)

typedef __bf16 bfv8 __attribute__((ext_vector_type(8)));
typedef float  f4   __attribute__((ext_vector_type(4)));
typedef float  f8   __attribute__((ext_vector_type(8)));

// ---------------------------------------------------------------------------
// Kernel 1: convert GEMM operands to bf16 (assemble mem_full + zero pad;
// weights pre-scaled by C2). One thread = 8 elements. R12 lesson: conversion
// lives HERE (latency-insensitive streaming kernel), never in the GEMM
// staging path (conditional f32 loads + cvt chains there serialized the
// pipeline 10x: R6=104us, R12=100us vs R11=fast).
// ---------------------------------------------------------------------------
#define N_MF  (AROWS * 512 / 8)         // 270336
#define N_DEC (256 * 512 / 8)           // 16384
#define N_W   (1024 * 512 / 8)          // 65536
#define N_CVT (N_MF + N_DEC + 2 * N_W)  // 417792 = 1632*256

__global__ __launch_bounds__(256) void convert_all(
        const float* __restrict__ mem, const float* __restrict__ term,
        const float* __restrict__ dec_hid,
        const float* __restrict__ W_mem, const float* __restrict__ W_dec,
        __bf16* __restrict__ mfb, __bf16* __restrict__ decb,
        __bf16* __restrict__ wmb, __bf16* __restrict__ wdb) {
    int idx = blockIdx.x * 256 + threadIdx.x;
    float4 v0 = make_float4(0.f, 0.f, 0.f, 0.f), v1 = v0;
    float scale = 1.f;
    __bf16* dst;
    if (idx < N_MF) {
        int row = idx >> 6;          // 64 chunks of 8 per 512-wide row
        int c8  = idx & 63;
        dst = mfb + (size_t)idx * 8;
        if (row < PM_ROWS) {
            int b = row / M1, m = row - b * M1;
            const float* src = (m == 0) ? (term + c8 * 8)
                                        : (mem + ((size_t)(b * MEM_LEN + m - 1)) * 512 + c8 * 8);
            v0 = ((const float4*)src)[0];
            v1 = ((const float4*)src)[1];
        } // else rows >= 4104 stay zero (GEMM pad)
    } else if (idx < N_MF + N_DEC) {
        int j = idx - N_MF;
        dst = decb + (size_t)j * 8;
        v0 = ((const float4*)dec_hid)[j * 2];
        v1 = ((const float4*)dec_hid)[j * 2 + 1];
    } else if (idx < N_MF + N_DEC + N_W) {
        int j = idx - N_MF - N_DEC;
        dst = wmb + (size_t)j * 8;
        v0 = ((const float4*)W_mem)[j * 2];
        v1 = ((const float4*)W_mem)[j * 2 + 1];
        scale = C2F;
    } else {
        int j = idx - N_MF - N_DEC - N_W;
        dst = wdb + (size_t)j * 8;
        v0 = ((const float4*)W_dec)[j * 2];
        v1 = ((const float4*)W_dec)[j * 2 + 1];
        scale = C2F;
    }
    bfv8 o;
    o[0] = (__bf16)(v0.x * scale); o[1] = (__bf16)(v0.y * scale);
    o[2] = (__bf16)(v0.z * scale); o[3] = (__bf16)(v0.w * scale);
    o[4] = (__bf16)(v1.x * scale); o[5] = (__bf16)(v1.y * scale);
    o[6] = (__bf16)(v1.z * scale); o[7] = (__bf16)(v1.w * scale);
    *(bfv8*)dst = o;
}

// ---------------------------------------------------------------------------
// Kernel 2: LDS-staged bf16 MFMA GEMM — R11's proven-fast structure, verbatim.
// Epilogue: Em bf16 (pm) / Ed f32 (pd). Key properties (all measured):
//  * staging loads UNCONDITIONAL bf16 16B, 8 lanes = 128B contiguous
//  * fully-unrolled kt loop => literal LDS buffer indices
//  * next-tile loads issued BEFORE current compute (counted vmcnt)
//  * T2 XOR chunk swizzle on both ds_write and ds_read (rule #21)
//  * chunked-bijective XCD swizzle (1120 = 8*140)
// Tile 64x64, BK=64, 4 waves (2x2) of 32x32; LDS 32KB.
// Layouts (HW-verified m89/m91): A/B frag lane l -> row (l&15), k=(l>>4)*8+j;
// C/D: col = l&15, row = (l>>4)*4 + reg.
// ---------------------------------------------------------------------------
__global__ __launch_bounds__(256, 4) void gemm_ls(
        const __bf16* __restrict__ mfb, const __bf16* __restrict__ decb,
        const __bf16* __restrict__ wmb, const __bf16* __restrict__ wdb,
        const float* __restrict__ b_mem, const float* __restrict__ b_dec,
        __bf16* __restrict__ pmb, float* __restrict__ pdf) {
    __shared__ __align__(16) __bf16 Als[2][64 * 64];   // 2 x 8KB
    __shared__ __align__(16) __bf16 Bls[2][64 * 64];   // 2 x 8KB

    int orig = blockIdx.x;                       // 0..1119
    int wg   = (orig & 7) * 140 + (orig >> 3);   // chunked XCD swizzle (8*140)
    int bx   = wg >> 4;                          // 0..69
    int by   = wg & 15;

    bool isMem = bx < 66;
    const __bf16* A  = isMem ? mfb : decb;
    const __bf16* Wb = isMem ? wmb : wdb;
    const float* bsel = isMem ? b_mem : b_dec;
    int row0 = isMem ? bx * 64 : (bx - 66) * 64;
    int n0b  = by * 64;

    int t = threadIdx.x;
    int r0 = t >> 3,          g0 = t & 7;
    int r1 = (t + 256) >> 3,  g1 = t & 7;
    int ds0 = r0 * 128 + ((g0 ^ (r0 & 7)) << 4);   // swizzled byte offsets
    int ds1 = r1 * 128 + ((g1 ^ (r1 & 7)) << 4);
    const __bf16* aSrc0 = A  + (size_t)(row0 + r0) * 512 + g0 * 8;
    const __bf16* aSrc1 = A  + (size_t)(row0 + r1) * 512 + g1 * 8;
    const __bf16* bSrc0 = Wb + (size_t)(n0b + r0) * 512 + g0 * 8;
    const __bf16* bSrc1 = Wb + (size_t)(n0b + r1) * 512 + g1 * 8;

    int w = t >> 6, l = t & 63;
    int m0w = (w >> 1) * 32, n0w = (w & 1) * 32;
    int lr = l & 15, lq = l >> 4;

    f4 acc[2][2] = {};

    // prologue: stage K-tile 0 into buf 0
    {
        bfv8 a0 = *(const bfv8*)(aSrc0);
        bfv8 a1 = *(const bfv8*)(aSrc1);
        bfv8 b0 = *(const bfv8*)(bSrc0);
        bfv8 b1 = *(const bfv8*)(bSrc1);
        *(bfv8*)((char*)&Als[0][0] + ds0) = a0;
        *(bfv8*)((char*)&Als[0][0] + ds1) = a1;
        *(bfv8*)((char*)&Bls[0][0] + ds0) = b0;
        *(bfv8*)((char*)&Bls[0][0] + ds1) = b1;
    }
    __syncthreads();

    #pragma unroll
    for (int kt = 0; kt < 8; ++kt) {
        const int cur = kt & 1;
        bfv8 na0, na1, nb0, nb1;
        if (kt < 7) {                      // issue next-tile loads EARLY
            const int kn = (kt + 1) * 64;
            na0 = *(const bfv8*)(aSrc0 + kn);
            na1 = *(const bfv8*)(aSrc1 + kn);
            nb0 = *(const bfv8*)(bSrc0 + kn);
            nb1 = *(const bfv8*)(bSrc1 + kn);
        }
        SCHED_FENCE();                     // keep load issue above compute
        // fragments: 8 ds_read_b128 (swizzled, conflict-free) then 8 MFMA
        bfv8 aF[2][2], bF[2][2];
        #pragma unroll
        for (int kk = 0; kk < 2; ++kk) {
            int g = kk * 4 + lq;
            #pragma unroll
            for (int i = 0; i < 2; ++i) {
                int rA = m0w + i * 16 + lr;
                aF[kk][i] = *(const bfv8*)((char*)&Als[cur][0] + rA * 128 + ((g ^ (rA & 7)) << 4));
                int rB = n0w + i * 16 + lr;
                bF[kk][i] = *(const bfv8*)((char*)&Bls[cur][0] + rB * 128 + ((g ^ (rB & 7)) << 4));
            }
        }
        #pragma unroll
        for (int kk = 0; kk < 2; ++kk) {
            acc[0][0] = __builtin_amdgcn_mfma_f32_16x16x32_bf16(aF[kk][0], bF[kk][0], acc[0][0], 0, 0, 0);
            acc[0][1] = __builtin_amdgcn_mfma_f32_16x16x32_bf16(aF[kk][0], bF[kk][1], acc[0][1], 0, 0, 0);
            acc[1][0] = __builtin_amdgcn_mfma_f32_16x16x32_bf16(aF[kk][1], bF[kk][0], acc[1][0], 0, 0, 0);
            acc[1][1] = __builtin_amdgcn_mfma_f32_16x16x32_bf16(aF[kk][1], bF[kk][1], acc[1][1], 0, 0, 0);
        }
        if (kt < 7) {                      // write next tile to other buffer
            const int nxt = cur ^ 1;
            *(bfv8*)((char*)&Als[nxt][0] + ds0) = na0;
            *(bfv8*)((char*)&Als[nxt][0] + ds1) = na1;
            *(bfv8*)((char*)&Bls[nxt][0] + ds0) = nb0;
            *(bfv8*)((char*)&Bls[nxt][0] + ds1) = nb1;
        }
        __syncthreads();
    }

    // epilogue: Em = exp2(acc + C2*bias) -> bf16 (pm); Ed -> f32 (pd)
    int crow = lq * 4;
    int ccol = lr;
    #pragma unroll
    for (int j = 0; j < 2; ++j) {
        int col = n0b + n0w + j * 16 + ccol;
        float bv = bsel[col] * C2F;
        #pragma unroll
        for (int i = 0; i < 2; ++i) {
            #pragma unroll
            for (int r = 0; r < 4; ++r) {
                int row = row0 + m0w + i * 16 + crow + r;
                float e = EXP2(acc[i][j][r] + bv);
                if (isMem) pmb[(size_t)row * HDIM + col] = (__bf16)e;
                else       pdf[(size_t)row * HDIM + col] = e;
            }
        }
    }
}

// ---------------------------------------------------------------------------
// Kernel 3: score[b,d,m] = SumW - sum_h 2*w[h]*rcp(1 + Em*Ed)
// 4-way rational combine: one rcp per 4 h-elements (t_i = 1+Em*Ed >= 1,
// positive, no cancellation; D <= ~2^120 f32-safe; D=inf -> rcp=0, N finite
// -> correct 0 limit). Per-4 cost: 14 VALU + 1 trans (was 8 VALU + 4 trans;
// trans = 16 cyc issue each, measured R10->R11).
// Em bf16 (cvt once per row, amortized over 4 d); Ed f32 in LDS (16KB).
// Grid: b(8) x dgroup(8, 4 d) x mchunk(17); b=bid&7 -> XCD.
// ---------------------------------------------------------------------------
__global__ __launch_bounds__(256, 4) void score8(
        const __bf16* __restrict__ pm, const float* __restrict__ pdf,
        const float* __restrict__ w_score,
        const unsigned char* __restrict__ mem_mask,
        const unsigned char* __restrict__ dec_mask,
        const unsigned char* __restrict__ dup_mask,
        float* __restrict__ sc) {
    __shared__ float pdl[4][HDIM];         // 16 KB (Ed, f32)
    int bid = blockIdx.x;
    int b    = bid & 7;
    int rest = bid >> 3;
    int dg   = rest & 7;
    int mc   = rest >> 3;                  // 0..16
    int t = threadIdx.x, w = t >> 6, l = t & 63;
    int bd0 = b * DEC_LEN + dg * 4;

    {   // cooperative stage: thread t copies 16 f32 of Ed row d = t>>6
        int d  = t >> 6;
        int h0 = (t & 63) * 16;
        const f4* src = (const f4*)(pdf + (size_t)(bd0 + d) * HDIM + h0);
        f4* dst = (f4*)&pdl[d][h0];
        dst[0] = src[0]; dst[1] = src[1]; dst[2] = src[2]; dst[3] = src[3];
    }

    f8 w22[2];
    float sumw_l = 0.f;
    #pragma unroll
    for (int half = 0; half < 2; ++half) {
        f8 wv = *(const f8*)(w_score + half * 512 + l * 8);
        #pragma unroll
        for (int j = 0; j < 8; ++j) {
            sumw_l += wv[j];
            w22[half][j] = wv[j] * 2.f;
        }
    }
    #pragma unroll
    for (int off = 32; off; off >>= 1) sumw_l += __shfl_xor(sumw_l, off, 64);
    float sumw_all = sumw_l;

    bool dm[4];
    #pragma unroll
    for (int d = 0; d < 4; ++d) dm[d] = dec_mask[bd0 + d] != 0;
    const unsigned char* dup0 = dup_mask + (size_t)bd0 * M1;

    __syncthreads();

    int mbase = mc * 32 + w * 8;
    for (int i = 0; i < 8; ++i) {
        int m = mbase + i;
        if (m >= M1) break;                // wave-uniform
        bool memm = (m > 0) && (mem_mask[b * MEM_LEN + m - 1] != 0);
        if (memm) {                        // wave-uniform skip (~10% rows)
            if (l == 0) {
                #pragma unroll
                for (int d = 0; d < 4; ++d)
                    sc[(size_t)(bd0 + d) * M1 + m] = NEG_BIG;
            }
            continue;
        }
        const __bf16* pmr = pm + ((size_t)(b * M1 + m)) * HDIM + l * 8;
        bfv8 p0 = *(const bfv8*)(pmr);
        bfv8 p1 = *(const bfv8*)(pmr + 512);
        f8 pf0, pf1;                       // cvt once per row (amortized 4x)
        #pragma unroll
        for (int j = 0; j < 8; ++j) { pf0[j] = (float)p0[j]; pf1[j] = (float)p1[j]; }
        float ac[4] = {};
        #pragma unroll
        for (int d = 0; d < 4; ++d) {
            f4 q0a = *(const f4*)&pdl[d][l * 8];
            f4 q0b = *(const f4*)&pdl[d][l * 8 + 4];
            f4 q1a = *(const f4*)&pdl[d][512 + l * 8];
            f4 q1b = *(const f4*)&pdl[d][512 + l * 8 + 4];
            #pragma unroll
            for (int j = 0; j < 4; ++j) {
                // 4 elements -> 1 rcp
                float t0 = fmaf(pf0[j],     q0a[j], 1.f);
                float t1 = fmaf(pf0[j + 4], q0b[j], 1.f);
                float t2 = fmaf(pf1[j],     q1a[j], 1.f);
                float t3 = fmaf(pf1[j + 4], q1b[j], 1.f);
                float D01 = t0 * t1;
                float D23 = t2 * t3;
                float N01 = fmaf(w22[0][j], t1, w22[0][j + 4] * t0);
                float N23 = fmaf(w22[1][j], t3, w22[1][j + 4] * t2);
                float N   = fmaf(N01, D23, N23 * D01);
                float D   = D01 * D23;
                ac[d] = fmaf(N, RCP(D), ac[d]);
            }
        }
        float a0 = ac[0], a1 = ac[1], a2 = ac[2], a3 = ac[3];
        #pragma unroll
        for (int off = 32; off; off >>= 1) {
            a0 += __shfl_xor(a0, off, 64);
            a1 += __shfl_xor(a1, off, 64);
            a2 += __shfl_xor(a2, off, 64);
            a3 += __shfl_xor(a3, off, 64);
        }
        float s[4];
        s[0] = sumw_all - a0;
        s[1] = sumw_all - a1;
        s[2] = sumw_all - a2;
        s[3] = sumw_all - a3;
        #pragma unroll
        for (int d = 0; d < 4; ++d) {
            bool kill = (!dm[d] && dup0[(size_t)d * M1 + m]);
            s[d] = kill ? NEG_BIG : s[d];
        }
        if (l == 0) {
            #pragma unroll
            for (int d = 0; d < 4; ++d)
                sc[(size_t)(bd0 + d) * M1 + m] = s[d];
        }
    }
}

// ---------------------------------------------------------------------------
// Kernel 4: row-wise log_softmax over 513 entries. One block per (b,d).
// ---------------------------------------------------------------------------
__global__ __launch_bounds__(512) void softmax_k(const float* __restrict__ sc,
                                                 float* __restrict__ out) {
    __shared__ float red[512];
    int bd = blockIdx.x, t = threadIdx.x;
    const float* row = sc + (size_t)bd * M1;
    float v = row[t];
    float v512 = row[512];
    float lm = (t == 0) ? fmaxf(v, v512) : v;
    red[t] = lm;
    __syncthreads();
    for (int s = 256; s > 0; s >>= 1) {
        if (t < s) red[t] = fmaxf(red[t], red[t + s]);
        __syncthreads();
    }
    float mx = red[0];
    __syncthreads();
    float le = __expf(v - mx);             // exp(NEG_BIG - mx) == 0 exactly
    if (t == 0) le += __expf(v512 - mx);
    red[t] = le;
    __syncthreads();
    for (int s = 256; s > 0; s >>= 1) {
        if (t < s) red[t] += red[t + s];
        __syncthreads();
    }
    float lse = mx + __logf(red[0]);
    float* orow = out + (size_t)bd * M1;
    orow[t] = v - lse;
    if (t == 0) orow[512] = v512 - lse;
}

// ---------------------------------------------------------------------------
extern "C" void kernel_launch(void* const* d_in, const int* in_sizes, int n_in,
                              void* d_out, int out_size, void* d_ws, size_t ws_size,
                              hipStream_t stream) {
    const float* mem      = (const float*)d_in[0];
    const float* dec_hid  = (const float*)d_in[1];
    const unsigned char* mem_mask = (const unsigned char*)d_in[2];
    const unsigned char* dec_mask = (const unsigned char*)d_in[3];
    const unsigned char* dup_mask = (const unsigned char*)d_in[4];
    const float* term     = (const float*)d_in[5];
    const float* W_mem    = (const float*)d_in[6];
    const float* b_mem    = (const float*)d_in[7];
    const float* W_dec    = (const float*)d_in[8];
    const float* b_dec    = (const float*)d_in[9];
    const float* w_score  = (const float*)d_in[10];
    // d_in[11] = b_score : unused (log_softmax is shift-invariant)

    float* out = (float*)d_out;
    char* ws = (char*)d_ws;
    __bf16* mfb  = (__bf16*)ws;                              // 4224*512*2  = 4,325,376
    __bf16* decb = mfb + (size_t)AROWS * 512;                //  256*512*2  =   262,144
    __bf16* wmb  = decb + (size_t)256 * 512;                 // 1024*512*2  = 1,048,576
    __bf16* wdb  = wmb + (size_t)1024 * 512;                 // 1024*512*2  = 1,048,576
    __bf16* pmb  = wdb + (size_t)1024 * 512;                 // 4224*1024*2 = 8,650,752
    float*  pdf  = (float*)(pmb + (size_t)AROWS * HDIM);     //  256*1024*4 = 1,048,576
    float*  sc   = pdf + (size_t)256 * HDIM;                 //  256*513*4  =   525,312

    convert_all<<<N_CVT / 256, 256, 0, stream>>>(mem, term, dec_hid, W_mem, W_dec,
                                                 mfb, decb, wmb, wdb);
    gemm_ls<<<1120, 256, 0, stream>>>(mfb, decb, wmb, wdb, b_mem, b_dec, pmb, pdf);
    score8<<<8 * 8 * 17, 256, 0, stream>>>(pmb, pdf, w_score,
                                           mem_mask, dec_mask, dup_mask, sc);
    softmax_k<<<B * DEC_LEN, 512, 0, stream>>>(sc, out);
}